// Round 12
// baseline (23.404 us; speedup 1.0000x reference)
//
#include <hip/hip_runtime.h>
#include <math.h>

#define DIMQ 16
#define HID  128
#define SPB  32          // samples per block (8 waves; each wave owns ONE 16-h tile, all samples)
#define NTHREADS 512

typedef __attribute__((ext_vector_type(8))) _Float16 f16x8;  // MFMA A/B frag (4 VGPRs)
typedef __attribute__((ext_vector_type(4))) _Float16 f16x4;  // packed b64 store
typedef __attribute__((ext_vector_type(4))) float f32x4;     // MFMA acc

// f16 row strides (elements)
#define USTR 280         // usp[32][280]: u at h'=0..127, -sp at h'=128..255
#define SSTR 136         // sst[32][136]: s values (validated stride)

// LDS layout (bytes). Mscr overlays everything AFTER barrier #2.
#define OFF_YBF  0       // f16[32][32]  =  2048
#define OFF_USP  2048    // f16[32][280] = 17920 -> 19968
#define OFF_SST  19968   // f16[32][136] =  8704 -> 28672
#define OFF_MSCR 0       // f32 32*320 = 40960 (post-barrier-2 overlay)
#define LDS_BYTES 40960  // 160KiB/4 exactly -> 4 blocks/CU

// XOR-swizzle inside each sample's 320-f32 M-scratch (v7-validated).
__device__ __forceinline__ int mswz(int s, int off) {
    return s * 320 + (off ^ ((s & 7) << 2));
}

// ---- one-time weight prep: W1 f32 -> f16 in two layouts in d_ws ----
// Wh[128][32] row-major; G[8][4][16][8]: G[kk][grp][j][e] =
//   kk<4 : A[32*kk+8*grp+e][j]   (A^T fragment data, rhs GEMM kc=0..3)
//   kk>=4: B[32*(kk-4)+8*grp+e][j]  (B^T data, rhs kc=4..7 AND M-GEMM bfrag)
__global__ void lag_prep_kernel(const float* __restrict__ W1,
                                _Float16* __restrict__ wsp)
{
    const int idx = blockIdx.x * 256 + threadIdx.x;   // 0..4095
    const float v = W1[idx];
    const _Float16 hv = (_Float16)v;
    _Float16* Wh = wsp;            // [128][32]
    _Float16* G  = wsp + 4096;     // [8][4][16][8]
    const int h = idx >> 5, k = idx & 31;
    Wh[idx] = hv;
    const int kc  = h >> 5;          // 0..3
    const int grp = (h >> 3) & 3;
    const int e   = h & 7;
    const int j   = (k < 16) ? k : (k - 16);
    const int kk  = (k < 16) ? kc : (kc + 4);
    G[((kk * 4 + grp) * 16 + j) * 8 + e] = hv;
}

__global__ __launch_bounds__(NTHREADS, 4)
void lag_accel_kernel(const float* __restrict__ y,      // [BATCH][32]
                      const _Float16* __restrict__ wsp, // Wh + G (L2-hot)
                      const float* __restrict__ b1,     // [128]
                      const float* __restrict__ w2,     // [128]
                      float* __restrict__ out)          // [BATCH][16]
{
    __shared__ __align__(16) char smem[LDS_BYTES];
    _Float16* Ybf = (_Float16*)(smem + OFF_YBF);   // [32][32]  f16 sample-major y
    _Float16* usp = (_Float16*)(smem + OFF_USP);   // [32][280]: u / -sp
    _Float16* sst = (_Float16*)(smem + OFF_SST);   // [32][136]: s

    const f16x8* Wh8 = (const f16x8*)wsp;          // [128][4] frags
    const f16x8* G8  = (const f16x8*)(wsp + 4096); // [8][4][16] frags

    const int tid = threadIdx.x;
    const long long s0 = (long long)blockIdx.x * SPB;

    // ---- staging: y only (W-side data comes from global/L2) ----
    for (int idx = tid; idx < SPB * 32; idx += NTHREADS)
        Ybf[idx] = (_Float16)y[s0 * 32 + idx];

    const int wave = tid >> 6;
    const int lane = tid & 63;
    const int grp  = lane >> 4;      // MFMA quadrant (k-slice / D row-block)
    const int j    = lane & 15;      // MFMA m/n index
    const int ht   = wave;           // this wave's h-tile (h = 16*ht .. 16*ht+15)

    // up-front global frag loads (L2-hot, issued before the barrier)
    f16x8 aW  = Wh8[(ht * 16 + j) * 4 + grp];
    f16x8 aAl = Wh8[(ht * 16 + j) * 4 + (grp & 1)];
    f16x8 aA;
#pragma unroll
    for (int e = 0; e < 8; ++e) aA[e] = (grp >= 2) ? aAl[e] : (_Float16)0.0f;
    float4 b1v = *(const float4*)&b1[ht * 16 + (grp << 2)];
    float4 w2v = *(const float4*)&w2[ht * 16 + (grp << 2)];

    __syncthreads();   // barrier 0: Ybf staged

    // ---- z/aqd GEMM: z = [A|B].y + b1 and aqd = [0|A].y (K=32), per h-tile ----
    f32x4 zacc[2], aacc[2];
    {
        f32x4 ci; ci[0] = b1v.x; ci[1] = b1v.y; ci[2] = b1v.z; ci[3] = b1v.w;
        f32x4 zf = {0.0f, 0.0f, 0.0f, 0.0f};
        f16x8 yf0 = *(const f16x8*)&Ybf[(0 * 16 + j) * 32 + (grp << 3)];
        f16x8 yf1 = *(const f16x8*)&Ybf[(1 * 16 + j) * 32 + (grp << 3)];
        zacc[0] = __builtin_amdgcn_mfma_f32_16x16x32_f16(aW, yf0, ci, 0, 0, 0);
        zacc[1] = __builtin_amdgcn_mfma_f32_16x16x32_f16(aW, yf1, ci, 0, 0, 0);
        aacc[0] = __builtin_amdgcn_mfma_f32_16x16x32_f16(aA, yf0, zf, 0, 0, 0);
        aacc[1] = __builtin_amdgcn_mfma_f32_16x16x32_f16(aA, yf1, zf, 0, 0, 0);
    }

    // ---- elementwise: t,u,s,sp per (h = 16ht+4grp+r, smp = 16st+j); stage f16 ----
    const int h4 = ht * 16 + (grp << 2);
#define EWST(st)                                                         \
    {                                                                    \
        _Float16 su[4], sn[4], sv[4];                                    \
        _Pragma("unroll")                                                \
        for (int r = 0; r < 4; ++r) {                                    \
            float z  = zacc[st][r], aq = aacc[st][r];                    \
            float w2c = (r == 0) ? w2v.x : (r == 1) ? w2v.y               \
                       : (r == 2) ? w2v.z : w2v.w;                       \
            float e  = __expf(2.0f * z);                                 \
            float rr = 2.0f * __builtin_amdgcn_rcpf(e + 1.0f);           \
            float t  = 1.0f - rr;                                        \
            float u  = w2c * (rr * (2.0f - rr));                         \
            float s  = -2.0f * t * u;                                    \
            float sp = s * aq;                                           \
            su[r] = (_Float16)u; sn[r] = (_Float16)(-sp);                \
            sv[r] = (_Float16)s;                                         \
        }                                                                \
        const int smp2 = (st) * 16 + j;                                  \
        f16x4 pa = {su[0], su[1], su[2], su[3]};                         \
        f16x4 pb = {sn[0], sn[1], sn[2], sn[3]};                         \
        f16x4 pc = {sv[0], sv[1], sv[2], sv[3]};                         \
        *(f16x4*)&usp[smp2 * USTR + h4]       = pa;                      \
        *(f16x4*)&usp[smp2 * USTR + 128 + h4] = pb;                      \
        *(f16x4*)&sst[smp2 * SSTR + h4]       = pc;                      \
    }
    EWST(0)
    EWST(1)
#undef EWST

    __syncthreads();   // barrier 1: u/-sp/s staged by all h-tiles

    // ---- rhs GEMM (waves 0,1): rhs = [A^T|B^T].[u;-sp], K=256; A-op from global G ----
    f32x4 racc = {0.0f, 0.0f, 0.0f, 0.0f};
    if (wave < 2) {
#pragma unroll
        for (int kc = 0; kc < 8; ++kc) {
            f16x8 af = G8[(kc * 4 + grp) * 16 + j];
            f16x8 bf = *(const f16x8*)&usp[(wave * 16 + j) * USTR + (kc << 5) + (grp << 3)];
            racc = __builtin_amdgcn_mfma_f32_16x16x32_f16(af, bf, racc, 0, 0, 0);
        }
    }

    // ---- M = I + B~^T diag(s) B~ via MFMA; bfrag from global G, sfrag from LDS ----
    f32x4 acc[4];
    {
        f32x4 ident;
#pragma unroll
        for (int r = 0; r < 4; ++r) ident[r] = ((grp << 2) + r == j) ? 1.0f : 0.0f;
#pragma unroll
        for (int gs = 0; gs < 4; ++gs) acc[gs] = ident;
    }
#pragma unroll
    for (int kc = 0; kc < 4; ++kc) {
        f16x8 bfrag = G8[((kc + 4) * 4 + grp) * 16 + j];
#pragma unroll
        for (int gs = 0; gs < 4; ++gs) {
            f16x8 sfrag = *(const f16x8*)&sst[(wave * 4 + gs) * SSTR + (kc << 5) + (grp << 3)];
            f16x8 afrag = sfrag * bfrag;   // v_pk_mul_f16 x4
            acc[gs] = __builtin_amdgcn_mfma_f32_16x16x32_f16(afrag, bfrag, acc[gs], 0, 0, 0);
        }
    }

    __syncthreads();   // barrier 2: all reads of Ybf/usp/sst done -> Mscr overlay

    float* Mscr = (float*)(smem + OFF_MSCR);
    // M symmetric: D(rows 4grp..4grp+3, col j) == M[j][4grp..4grp+3] -> one b128/sample.
#pragma unroll
    for (int gs = 0; gs < 4; ++gs) {
        float4 v;
        v.x = acc[gs][0]; v.y = acc[gs][1]; v.z = acc[gs][2]; v.w = acc[gs][3];
        *(float4*)&Mscr[mswz(wave * 4 + gs, j * 20 + (grp << 2))] = v;
    }

    __syncthreads();   // barrier 3: scratch complete

    // ---- solve (waves 0,1; 16 samples each; 4 lanes/sample, 4 rows/lane) ----
    if (wave >= 2) return;
    const int sl = lane & 15;            // sample within this wave's half
    const int rb = lane >> 4;            // row block (rows 4rb..4rb+3)
    const int s  = wave * 16 + sl;       // sample within block

    float M4[4][16], r4[4], d4[4];
#pragma unroll
    for (int r = 0; r < 4; ++r) {
        const int ro = (4 * rb + r) * 20;
        float4 v0 = *(const float4*)&Mscr[mswz(s, ro + 0)];
        float4 v1 = *(const float4*)&Mscr[mswz(s, ro + 4)];
        float4 v2 = *(const float4*)&Mscr[mswz(s, ro + 8)];
        float4 v3 = *(const float4*)&Mscr[mswz(s, ro + 12)];
        M4[r][0]=v0.x; M4[r][1]=v0.y; M4[r][2]=v0.z; M4[r][3]=v0.w;
        M4[r][4]=v1.x; M4[r][5]=v1.y; M4[r][6]=v1.z; M4[r][7]=v1.w;
        M4[r][8]=v2.x; M4[r][9]=v2.y; M4[r][10]=v2.z; M4[r][11]=v2.w;
        M4[r][12]=v3.x; M4[r][13]=v3.y; M4[r][14]=v3.z; M4[r][15]=v3.w;
        r4[r] = racc[r];                 // rhs already in the right lane/reg
        d4[r] = 1.0f;
    }

    // Gauss-Jordan, non-normalizing, triangular skip (v7-validated).
#pragma unroll
    for (int k = 0; k < 16; ++k) {
        const int src = sl + ((k >> 2) << 4);
        float piv = __shfl(M4[k & 3][k], src, 64);
        float rk  = __shfl(r4[k & 3], src, 64);
        float invp = __builtin_amdgcn_rcpf(piv);
        invp = invp * (2.0f - piv * invp);
        float f[4];
#pragma unroll
        for (int r = 0; r < 4; ++r) {
            float fr = M4[r][k] * invp;
            const bool isk = ((rb << 2) + r) == k;
            f[r]  = isk ? 0.0f : fr;
            d4[r] = isk ? piv : d4[r];
            r4[r] = fmaf(-f[r], rk, r4[r]);
        }
#pragma unroll
        for (int i = k + 1; i < 16; ++i) {
            float p = __shfl(M4[k & 3][i], src, 64);
            M4[0][i] = fmaf(-f[0], p, M4[0][i]);
            M4[1][i] = fmaf(-f[1], p, M4[1][i]);
            M4[2][i] = fmaf(-f[2], p, M4[2][i]);
            M4[3][i] = fmaf(-f[3], p, M4[3][i]);
        }
    }

    float4 xo;
    {
        float i0 = __builtin_amdgcn_rcpf(d4[0]); i0 = i0 * (2.0f - d4[0] * i0);
        float i1 = __builtin_amdgcn_rcpf(d4[1]); i1 = i1 * (2.0f - d4[1] * i1);
        float i2 = __builtin_amdgcn_rcpf(d4[2]); i2 = i2 * (2.0f - d4[2] * i2);
        float i3 = __builtin_amdgcn_rcpf(d4[3]); i3 = i3 * (2.0f - d4[3] * i3);
        xo.x = r4[0] * i0; xo.y = r4[1] * i1; xo.z = r4[2] * i2; xo.w = r4[3] * i3;
    }
    *(float4*)&out[(s0 + s) * DIMQ + (rb << 2)] = xo;
}

extern "C" void kernel_launch(void* const* d_in, const int* in_sizes, int n_in,
                              void* d_out, int out_size, void* d_ws, size_t ws_size,
                              hipStream_t stream) {
    const float* y  = (const float*)d_in[0];
    const float* W1 = (const float*)d_in[1];
    const float* b1 = (const float*)d_in[2];
    const float* w2 = (const float*)d_in[3];
    float* out = (float*)d_out;
    _Float16* wsp = (_Float16*)d_ws;             // 16 KB used: Wh[4096] + G[4096]
    const int batch = in_sizes[0] / 32;          // 32768
    const int blocks = (batch + SPB - 1) / SPB;  // 1024
    lag_prep_kernel<<<16, 256, 0, stream>>>(W1, wsp);
    lag_accel_kernel<<<blocks, NTHREADS, 0, stream>>>(y, wsp, b1, w2, out);
}

// Round 13
// 20.424 us; speedup vs baseline: 1.1459x; 1.1459x over previous
//
#include <hip/hip_runtime.h>
#include <math.h>

#define DIMQ 16
#define HID  128
#define SPB  32          // samples per block (8 waves; each wave owns ONE 16-h tile, all samples)
#define NTHREADS 512

typedef __attribute__((ext_vector_type(8))) _Float16 f16x8;  // MFMA A/B frag (4 VGPRs)
typedef __attribute__((ext_vector_type(4))) _Float16 f16x4;  // packed b64 store
typedef __attribute__((ext_vector_type(4))) float f32x4;     // MFMA acc

// f16 strides (elements)
#define ASTR 280         // ABT[16][280]: [A^T | B^T], 560B row (16B-mult)
#define USTR 280         // usp[32][280]: u at h'=0..127, -sp at h'=128..255
#define SSTR 136         // sst[32][136]: s values

// LDS layout (bytes). Mscr overlays [0,40960) AFTER barrier #2 (all regions dead by then).
#define OFF_WFF  0       // f16 frag-major [8][4][16][8] = 8192
#define OFF_YFF  8192    // f16 frag-major [2][4][16][8] = 2048 -> 10240
#define OFF_ABT  10240   // f16[16][280] = 8960 -> 19200
#define OFF_USP  19200   // f16[32][280] = 17920 -> 37120
#define OFF_SST  37120   // f16[32][136] = 8704 -> 45824
#define OFF_MSCR 0       // f32 32*320 = 40960 (overlay)
#define LDS_BYTES 45824

// XOR-swizzle inside each sample's 320-f32 M-scratch (v7-validated).
__device__ __forceinline__ int mswz(int s, int off) {
    return s * 320 + (off ^ ((s & 7) << 2));
}
__device__ __forceinline__ f16x8 pack8(float4 a, float4 b) {
    f16x8 r;
    r[0]=(_Float16)a.x; r[1]=(_Float16)a.y; r[2]=(_Float16)a.z; r[3]=(_Float16)a.w;
    r[4]=(_Float16)b.x; r[5]=(_Float16)b.y; r[6]=(_Float16)b.z; r[7]=(_Float16)b.w;
    return r;
}

__global__ __launch_bounds__(NTHREADS, 4)
void lag_accel_kernel(const float* __restrict__ y,    // [BATCH][32]
                      const float* __restrict__ W1,   // [128][32]
                      const float* __restrict__ b1,   // [128]
                      const float* __restrict__ w2,   // [128]
                      float* __restrict__ out)        // [BATCH][16]
{
    __shared__ __align__(16) char smem[LDS_BYTES];
    _Float16* Wff = (_Float16*)(smem + OFF_WFF);   // frag-major W1 rows
    _Float16* Yff = (_Float16*)(smem + OFF_YFF);   // frag-major y
    _Float16* ABT = (_Float16*)(smem + OFF_ABT);   // [16][280]: [j][h]=A[h][j], [j][128+h]=B[h][j]
    _Float16* usp = (_Float16*)(smem + OFF_USP);   // [32][280]: u / -sp
    _Float16* sst = (_Float16*)(smem + OFF_SST);   // [32][136]: s

    const int tid = threadIdx.x;
    const long long s0 = (long long)blockIdx.x * SPB;

    // ---- staging (all vectorized b128/b64 writes) ----
    // Wff[ht][grp][j] frag = W1[(16ht+j)][8grp..+7]  (tid = ht*64+grp*16+j)
    {
        const int ht_ = tid >> 6, grp_ = (tid >> 4) & 3, j_ = tid & 15;
        const float4* src = (const float4*)(W1 + (ht_ * 16 + j_) * 32 + (grp_ << 3));
        *(f16x8*)&Wff[tid * 8] = pack8(src[0], src[1]);
    }
    // Yff[st][grp][j] frag = y[s0+16st+j][8grp..+7]  (256 threads, b64 halves)
    if (tid < 256) {
        const int st_ = tid >> 7, grp_ = (tid >> 5) & 3, j_ = (tid >> 1) & 15, hf = tid & 1;
        float4 v = *(const float4*)(y + (s0 + st_ * 16 + j_) * 32 + (grp_ << 3) + (hf << 2));
        f16x4 p; p[0]=(_Float16)v.x; p[1]=(_Float16)v.y; p[2]=(_Float16)v.z; p[3]=(_Float16)v.w;
        *(f16x4*)&Yff[(((st_ * 4 + grp_) * 16 + j_) << 3) + (hf << 2)] = p;
    }
    // ABT: column-wise W1 loads -> contiguous b128 writes. tid = hb*32 + k.
    {
        const int k = tid & 31, h0 = (tid >> 5) << 3;
        float v[8];
#pragma unroll
        for (int i = 0; i < 8; ++i) v[i] = W1[(h0 + i) * 32 + k];
        f16x8 p;
#pragma unroll
        for (int i = 0; i < 8; ++i) p[i] = (_Float16)v[i];
        const int j_ = (k < 16) ? k : (k - 16);
        const int off = (k < 16) ? h0 : (128 + h0);
        *(f16x8*)&ABT[j_ * ASTR + off] = p;
    }

    const int wave = tid >> 6;
    const int lane = tid & 63;
    const int grp  = lane >> 4;      // MFMA quadrant (k-slice / D row-block)
    const int j    = lane & 15;      // MFMA m/n index
    const int ht   = wave;           // this wave's h-tile (h = 16*ht .. 16*ht+15)

    // b1/w2: uniform global float4 (single-line broadcast per 16 lanes)
    float4 b1v = *(const float4*)&b1[ht * 16 + (grp << 2)];
    float4 w2v = *(const float4*)&w2[ht * 16 + (grp << 2)];

    __syncthreads();   // barrier 0: staging complete

    // ---- z/aqd GEMM: z = [A|B].y + b1 and aqd = [0|A].y (K=32), per h-tile ----
    f16x8 aW  = *(const f16x8*)&Wff[((ht * 4 + grp) * 16 + j) * 8];
    f16x8 aAl = *(const f16x8*)&Wff[((ht * 4 + (grp & 1)) * 16 + j) * 8];
    f16x8 aA;
#pragma unroll
    for (int e = 0; e < 8; ++e) aA[e] = (grp >= 2) ? aAl[e] : (_Float16)0.0f;

    f32x4 zacc[2], aacc[2];
    {
        f32x4 ci; ci[0] = b1v.x; ci[1] = b1v.y; ci[2] = b1v.z; ci[3] = b1v.w;
        f32x4 zf = {0.0f, 0.0f, 0.0f, 0.0f};
        f16x8 yf0 = *(const f16x8*)&Yff[((0 * 4 + grp) * 16 + j) * 8];
        f16x8 yf1 = *(const f16x8*)&Yff[((1 * 4 + grp) * 16 + j) * 8];
        zacc[0] = __builtin_amdgcn_mfma_f32_16x16x32_f16(aW, yf0, ci, 0, 0, 0);
        zacc[1] = __builtin_amdgcn_mfma_f32_16x16x32_f16(aW, yf1, ci, 0, 0, 0);
        aacc[0] = __builtin_amdgcn_mfma_f32_16x16x32_f16(aA, yf0, zf, 0, 0, 0);
        aacc[1] = __builtin_amdgcn_mfma_f32_16x16x32_f16(aA, yf1, zf, 0, 0, 0);
    }

    // ---- elementwise: t,u,s,sp per (h = 16ht+4grp+r, smp = 16st+j); stage f16 ----
    const int h4 = ht * 16 + (grp << 2);
#define EWST(st)                                                         \
    {                                                                    \
        _Float16 su[4], sn[4], sv[4];                                    \
        _Pragma("unroll")                                                \
        for (int r = 0; r < 4; ++r) {                                    \
            float z  = zacc[st][r], aq = aacc[st][r];                    \
            float w2c = (r == 0) ? w2v.x : (r == 1) ? w2v.y               \
                       : (r == 2) ? w2v.z : w2v.w;                       \
            float e  = __expf(2.0f * z);                                 \
            float rr = 2.0f * __builtin_amdgcn_rcpf(e + 1.0f);           \
            float t  = 1.0f - rr;                                        \
            float u  = w2c * (rr * (2.0f - rr));                         \
            float s  = -2.0f * t * u;                                    \
            float sp = s * aq;                                           \
            su[r] = (_Float16)u; sn[r] = (_Float16)(-sp);                \
            sv[r] = (_Float16)s;                                         \
        }                                                                \
        const int smp2 = (st) * 16 + j;                                  \
        f16x4 pa = {su[0], su[1], su[2], su[3]};                         \
        f16x4 pb = {sn[0], sn[1], sn[2], sn[3]};                         \
        f16x4 pc = {sv[0], sv[1], sv[2], sv[3]};                         \
        *(f16x4*)&usp[smp2 * USTR + h4]       = pa;                      \
        *(f16x4*)&usp[smp2 * USTR + 128 + h4] = pb;                      \
        *(f16x4*)&sst[smp2 * SSTR + h4]       = pc;                      \
    }
    EWST(0)
    EWST(1)
#undef EWST

    __syncthreads();   // barrier 1: u/-sp/s staged by all h-tiles

    // ---- rhs GEMM (waves 0,1): rhs = [A^T|B^T].[u;-sp], K=256; D lands in solve layout ----
    f32x4 racc = {0.0f, 0.0f, 0.0f, 0.0f};
    if (wave < 2) {
#pragma unroll
        for (int kc = 0; kc < 8; ++kc) {
            f16x8 af = *(const f16x8*)&ABT[j * ASTR + (kc << 5) + (grp << 3)];
            f16x8 bf = *(const f16x8*)&usp[(wave * 16 + j) * USTR + (kc << 5) + (grp << 3)];
            racc = __builtin_amdgcn_mfma_f32_16x16x32_f16(af, bf, racc, 0, 0, 0);
        }
    }

    // ---- M = I + B~^T diag(s) B~ via MFMA; afrag = s (*) B via v_pk_mul_f16 ----
    f32x4 acc[4];
    {
        f32x4 ident;
#pragma unroll
        for (int r = 0; r < 4; ++r) ident[r] = ((grp << 2) + r == j) ? 1.0f : 0.0f;
#pragma unroll
        for (int gs = 0; gs < 4; ++gs) acc[gs] = ident;
    }
#pragma unroll
    for (int kc = 0; kc < 4; ++kc) {
        f16x8 bfrag = *(const f16x8*)&ABT[j * ASTR + 128 + (kc << 5) + (grp << 3)];
#pragma unroll
        for (int gs = 0; gs < 4; ++gs) {
            f16x8 sfrag = *(const f16x8*)&sst[(wave * 4 + gs) * SSTR + (kc << 5) + (grp << 3)];
            f16x8 afrag = sfrag * bfrag;   // v_pk_mul_f16 x4
            acc[gs] = __builtin_amdgcn_mfma_f32_16x16x32_f16(afrag, bfrag, acc[gs], 0, 0, 0);
        }
    }

    __syncthreads();   // barrier 2: all reads of Wff/Yff/ABT/usp/sst done -> Mscr overlay

    float* Mscr = (float*)(smem + OFF_MSCR);
    // M symmetric: D(rows 4grp..4grp+3, col j) == M[j][4grp..4grp+3] -> one b128/sample.
#pragma unroll
    for (int gs = 0; gs < 4; ++gs) {
        float4 v;
        v.x = acc[gs][0]; v.y = acc[gs][1]; v.z = acc[gs][2]; v.w = acc[gs][3];
        *(float4*)&Mscr[mswz(wave * 4 + gs, j * 20 + (grp << 2))] = v;
    }

    __syncthreads();   // barrier 3: scratch complete

    // ---- solve (waves 0,1; 16 samples each; 4 lanes/sample, 4 rows/lane) ----
    if (wave >= 2) return;
    const int sl = lane & 15;            // sample within this wave's half
    const int rb = lane >> 4;            // row block (rows 4rb..4rb+3)
    const int s  = wave * 16 + sl;       // sample within block

    float M4[4][16], r4[4], d4[4];
#pragma unroll
    for (int r = 0; r < 4; ++r) {
        const int ro = (4 * rb + r) * 20;
        float4 v0 = *(const float4*)&Mscr[mswz(s, ro + 0)];
        float4 v1 = *(const float4*)&Mscr[mswz(s, ro + 4)];
        float4 v2 = *(const float4*)&Mscr[mswz(s, ro + 8)];
        float4 v3 = *(const float4*)&Mscr[mswz(s, ro + 12)];
        M4[r][0]=v0.x; M4[r][1]=v0.y; M4[r][2]=v0.z; M4[r][3]=v0.w;
        M4[r][4]=v1.x; M4[r][5]=v1.y; M4[r][6]=v1.z; M4[r][7]=v1.w;
        M4[r][8]=v2.x; M4[r][9]=v2.y; M4[r][10]=v2.z; M4[r][11]=v2.w;
        M4[r][12]=v3.x; M4[r][13]=v3.y; M4[r][14]=v3.z; M4[r][15]=v3.w;
        r4[r] = racc[r];                 // rhs already in the right lane/reg
        d4[r] = 1.0f;
    }

    // Gauss-Jordan, non-normalizing, triangular skip (v7-validated).
#pragma unroll
    for (int k = 0; k < 16; ++k) {
        const int src = sl + ((k >> 2) << 4);
        float piv = __shfl(M4[k & 3][k], src, 64);
        float rk  = __shfl(r4[k & 3], src, 64);
        float invp = __builtin_amdgcn_rcpf(piv);
        invp = invp * (2.0f - piv * invp);
        float f[4];
#pragma unroll
        for (int r = 0; r < 4; ++r) {
            float fr = M4[r][k] * invp;
            const bool isk = ((rb << 2) + r) == k;
            f[r]  = isk ? 0.0f : fr;
            d4[r] = isk ? piv : d4[r];
            r4[r] = fmaf(-f[r], rk, r4[r]);
        }
#pragma unroll
        for (int i = k + 1; i < 16; ++i) {
            float p = __shfl(M4[k & 3][i], src, 64);
            M4[0][i] = fmaf(-f[0], p, M4[0][i]);
            M4[1][i] = fmaf(-f[1], p, M4[1][i]);
            M4[2][i] = fmaf(-f[2], p, M4[2][i]);
            M4[3][i] = fmaf(-f[3], p, M4[3][i]);
        }
    }

    float4 xo;
    {
        float i0 = __builtin_amdgcn_rcpf(d4[0]); i0 = i0 * (2.0f - d4[0] * i0);
        float i1 = __builtin_amdgcn_rcpf(d4[1]); i1 = i1 * (2.0f - d4[1] * i1);
        float i2 = __builtin_amdgcn_rcpf(d4[2]); i2 = i2 * (2.0f - d4[2] * i2);
        float i3 = __builtin_amdgcn_rcpf(d4[3]); i3 = i3 * (2.0f - d4[3] * i3);
        xo.x = r4[0] * i0; xo.y = r4[1] * i1; xo.z = r4[2] * i2; xo.w = r4[3] * i3;
    }
    *(float4*)&out[(s0 + s) * DIMQ + (rb << 2)] = xo;
}

extern "C" void kernel_launch(void* const* d_in, const int* in_sizes, int n_in,
                              void* d_out, int out_size, void* d_ws, size_t ws_size,
                              hipStream_t stream) {
    const float* y  = (const float*)d_in[0];
    const float* W1 = (const float*)d_in[1];
    const float* b1 = (const float*)d_in[2];
    const float* w2 = (const float*)d_in[3];
    float* out = (float*)d_out;
    const int batch = in_sizes[0] / 32;          // 32768
    const int blocks = (batch + SPB - 1) / SPB;  // 1024
    lag_accel_kernel<<<blocks, NTHREADS, 0, stream>>>(y, W1, b1, w2, out);
}

// Round 14
// 19.205 us; speedup vs baseline: 1.2186x; 1.0634x over previous
//
#include <hip/hip_runtime.h>
#include <math.h>

#define DIMQ 16
#define HID  128
#define SPB  32          // samples per block (8 waves; each wave owns ONE 16-h tile, all samples)
#define NTHREADS 512

typedef __attribute__((ext_vector_type(8))) _Float16 f16x8;  // MFMA A/B frag (4 VGPRs)
typedef __attribute__((ext_vector_type(4))) _Float16 f16x4;  // packed b64 store
typedef __attribute__((ext_vector_type(4))) float f32x4;     // MFMA acc
typedef __attribute__((ext_vector_type(2))) float v2f;       // packed f32 (v_pk_fma_f32)

// f16 strides (elements)
#define ASTR 280         // ABT[16][280]: [A^T | B^T], 560B row (16B-mult)
#define USTR 280         // usp[32][280]: u at h'=0..127, -sp at h'=128..255
#define SSTR 136         // sst[32][136]: s values

// LDS layout (bytes). Mscr overlays [0,40960) AFTER barrier #2 (all regions dead by then).
#define OFF_WFF  0       // f16 frag-major [8][4][16][8] = 8192
#define OFF_YFF  8192    // f16 frag-major [2][4][16][8] = 2048 -> 10240
#define OFF_ABT  10240   // f16[16][280] = 8960 -> 19200
#define OFF_USP  19200   // f16[32][280] = 17920 -> 37120
#define OFF_SST  37120   // f16[32][136] = 8704 -> 45824
#define OFF_MSCR 0       // f32 32*320 = 40960 (overlay)
#define LDS_BYTES 45824

// XOR-swizzle inside each sample's 320-f32 M-scratch (v7-validated).
__device__ __forceinline__ int mswz(int s, int off) {
    return s * 320 + (off ^ ((s & 7) << 2));
}
__device__ __forceinline__ f16x8 pack8(float4 a, float4 b) {
    f16x8 r;
    r[0]=(_Float16)a.x; r[1]=(_Float16)a.y; r[2]=(_Float16)a.z; r[3]=(_Float16)a.w;
    r[4]=(_Float16)b.x; r[5]=(_Float16)b.y; r[6]=(_Float16)b.z; r[7]=(_Float16)b.w;
    return r;
}

__global__ __launch_bounds__(NTHREADS, 4)
void lag_accel_kernel(const float* __restrict__ y,    // [BATCH][32]
                      const float* __restrict__ W1,   // [128][32]
                      const float* __restrict__ b1,   // [128]
                      const float* __restrict__ w2,   // [128]
                      float* __restrict__ out)        // [BATCH][16]
{
    __shared__ __align__(16) char smem[LDS_BYTES];
    _Float16* Wff = (_Float16*)(smem + OFF_WFF);   // frag-major W1 rows
    _Float16* Yff = (_Float16*)(smem + OFF_YFF);   // frag-major y
    _Float16* ABT = (_Float16*)(smem + OFF_ABT);   // [16][280]: [j][h]=A[h][j], [j][128+h]=B[h][j]
    _Float16* usp = (_Float16*)(smem + OFF_USP);   // [32][280]: u / -sp
    _Float16* sst = (_Float16*)(smem + OFF_SST);   // [32][136]: s

    const int tid = threadIdx.x;
    const long long s0 = (long long)blockIdx.x * SPB;

    // ---- staging (all vectorized b128/b64 writes) ----
    {
        const int ht_ = tid >> 6, grp_ = (tid >> 4) & 3, j_ = tid & 15;
        const float4* src = (const float4*)(W1 + (ht_ * 16 + j_) * 32 + (grp_ << 3));
        *(f16x8*)&Wff[tid * 8] = pack8(src[0], src[1]);
    }
    if (tid < 256) {
        const int st_ = tid >> 7, grp_ = (tid >> 5) & 3, j_ = (tid >> 1) & 15, hf = tid & 1;
        float4 v = *(const float4*)(y + (s0 + st_ * 16 + j_) * 32 + (grp_ << 3) + (hf << 2));
        f16x4 p; p[0]=(_Float16)v.x; p[1]=(_Float16)v.y; p[2]=(_Float16)v.z; p[3]=(_Float16)v.w;
        *(f16x4*)&Yff[(((st_ * 4 + grp_) * 16 + j_) << 3) + (hf << 2)] = p;
    }
    {
        const int k = tid & 31, h0 = (tid >> 5) << 3;
        float v[8];
#pragma unroll
        for (int i = 0; i < 8; ++i) v[i] = W1[(h0 + i) * 32 + k];
        f16x8 p;
#pragma unroll
        for (int i = 0; i < 8; ++i) p[i] = (_Float16)v[i];
        const int j_ = (k < 16) ? k : (k - 16);
        const int off = (k < 16) ? h0 : (128 + h0);
        *(f16x8*)&ABT[j_ * ASTR + off] = p;
    }

    const int wave = tid >> 6;
    const int lane = tid & 63;
    const int grp  = lane >> 4;      // MFMA quadrant (k-slice / D row-block)
    const int j    = lane & 15;      // MFMA m/n index
    const int ht   = wave;           // this wave's h-tile (h = 16*ht .. 16*ht+15)

    float4 b1v = *(const float4*)&b1[ht * 16 + (grp << 2)];
    float4 w2v = *(const float4*)&w2[ht * 16 + (grp << 2)];

    __syncthreads();   // barrier 0: staging complete

    // ---- z/aqd GEMM: z = [A|B].y + b1 and aqd = [0|A].y (K=32), per h-tile ----
    f16x8 aW  = *(const f16x8*)&Wff[((ht * 4 + grp) * 16 + j) * 8];
    f16x8 aAl = *(const f16x8*)&Wff[((ht * 4 + (grp & 1)) * 16 + j) * 8];
    f16x8 aA;
#pragma unroll
    for (int e = 0; e < 8; ++e) aA[e] = (grp >= 2) ? aAl[e] : (_Float16)0.0f;

    f32x4 zacc[2], aacc[2];
    {
        f32x4 ci; ci[0] = b1v.x; ci[1] = b1v.y; ci[2] = b1v.z; ci[3] = b1v.w;
        f32x4 zf = {0.0f, 0.0f, 0.0f, 0.0f};
        f16x8 yf0 = *(const f16x8*)&Yff[((0 * 4 + grp) * 16 + j) * 8];
        f16x8 yf1 = *(const f16x8*)&Yff[((1 * 4 + grp) * 16 + j) * 8];
        zacc[0] = __builtin_amdgcn_mfma_f32_16x16x32_f16(aW, yf0, ci, 0, 0, 0);
        zacc[1] = __builtin_amdgcn_mfma_f32_16x16x32_f16(aW, yf1, ci, 0, 0, 0);
        aacc[0] = __builtin_amdgcn_mfma_f32_16x16x32_f16(aA, yf0, zf, 0, 0, 0);
        aacc[1] = __builtin_amdgcn_mfma_f32_16x16x32_f16(aA, yf1, zf, 0, 0, 0);
    }

    // ---- elementwise: t,u,s,sp per (h = 16ht+4grp+r, smp = 16st+j); stage f16 ----
    const int h4 = ht * 16 + (grp << 2);
#define EWST(st)                                                         \
    {                                                                    \
        _Float16 su[4], sn[4], sv[4];                                    \
        _Pragma("unroll")                                                \
        for (int r = 0; r < 4; ++r) {                                    \
            float z  = zacc[st][r], aq = aacc[st][r];                    \
            float w2c = (r == 0) ? w2v.x : (r == 1) ? w2v.y               \
                       : (r == 2) ? w2v.z : w2v.w;                       \
            float e  = __expf(2.0f * z);                                 \
            float rr = 2.0f * __builtin_amdgcn_rcpf(e + 1.0f);           \
            float t  = 1.0f - rr;                                        \
            float u  = w2c * (rr * (2.0f - rr));                         \
            float s  = -2.0f * t * u;                                    \
            float sp = s * aq;                                           \
            su[r] = (_Float16)u; sn[r] = (_Float16)(-sp);                \
            sv[r] = (_Float16)s;                                         \
        }                                                                \
        const int smp2 = (st) * 16 + j;                                  \
        f16x4 pa = {su[0], su[1], su[2], su[3]};                         \
        f16x4 pb = {sn[0], sn[1], sn[2], sn[3]};                         \
        f16x4 pc = {sv[0], sv[1], sv[2], sv[3]};                         \
        *(f16x4*)&usp[smp2 * USTR + h4]       = pa;                      \
        *(f16x4*)&usp[smp2 * USTR + 128 + h4] = pb;                      \
        *(f16x4*)&sst[smp2 * SSTR + h4]       = pc;                      \
    }
    EWST(0)
    EWST(1)
#undef EWST

    __syncthreads();   // barrier 1: u/-sp/s staged by all h-tiles

    // ---- rhs GEMM (waves 0,1): rhs = [A^T|B^T].[u;-sp], K=256; D lands in solve layout ----
    f32x4 racc = {0.0f, 0.0f, 0.0f, 0.0f};
    if (wave < 2) {
#pragma unroll
        for (int kc = 0; kc < 8; ++kc) {
            f16x8 af = *(const f16x8*)&ABT[j * ASTR + (kc << 5) + (grp << 3)];
            f16x8 bf = *(const f16x8*)&usp[(wave * 16 + j) * USTR + (kc << 5) + (grp << 3)];
            racc = __builtin_amdgcn_mfma_f32_16x16x32_f16(af, bf, racc, 0, 0, 0);
        }
    }

    // ---- M = I + B~^T diag(s) B~ via MFMA; afrag = s (*) B via v_pk_mul_f16 ----
    f32x4 acc[4];
    {
        f32x4 ident;
#pragma unroll
        for (int r = 0; r < 4; ++r) ident[r] = ((grp << 2) + r == j) ? 1.0f : 0.0f;
#pragma unroll
        for (int gs = 0; gs < 4; ++gs) acc[gs] = ident;
    }
#pragma unroll
    for (int kc = 0; kc < 4; ++kc) {
        f16x8 bfrag = *(const f16x8*)&ABT[j * ASTR + 128 + (kc << 5) + (grp << 3)];
#pragma unroll
        for (int gs = 0; gs < 4; ++gs) {
            f16x8 sfrag = *(const f16x8*)&sst[(wave * 4 + gs) * SSTR + (kc << 5) + (grp << 3)];
            f16x8 afrag = sfrag * bfrag;   // v_pk_mul_f16 x4
            acc[gs] = __builtin_amdgcn_mfma_f32_16x16x32_f16(afrag, bfrag, acc[gs], 0, 0, 0);
        }
    }

    __syncthreads();   // barrier 2: all reads of Wff/Yff/ABT/usp/sst done -> Mscr overlay

    float* Mscr = (float*)(smem + OFF_MSCR);
#pragma unroll
    for (int gs = 0; gs < 4; ++gs) {
        float4 v;
        v.x = acc[gs][0]; v.y = acc[gs][1]; v.z = acc[gs][2]; v.w = acc[gs][3];
        *(float4*)&Mscr[mswz(wave * 4 + gs, j * 20 + (grp << 2))] = v;
    }

    __syncthreads();   // barrier 3: scratch complete

    // ---- solve (waves 0,1; 16 samples each; 4 lanes/sample, 4 rows/lane) ----
    // Packed-f32 Gauss-Jordan: rows as float2 pairs, v_pk_fma_f32 elimination.
    if (wave >= 2) return;
    const int sl = lane & 15;            // sample within this wave's half
    const int rb = lane >> 4;            // row block (rows 4rb..4rb+3)
    const int s  = wave * 16 + sl;       // sample within block

    v2f M2[4][8];
    float r4[4], d4[4];
#pragma unroll
    for (int r = 0; r < 4; ++r) {
        const int ro = (4 * rb + r) * 20;
        float4 v0 = *(const float4*)&Mscr[mswz(s, ro + 0)];
        float4 v1 = *(const float4*)&Mscr[mswz(s, ro + 4)];
        float4 v2 = *(const float4*)&Mscr[mswz(s, ro + 8)];
        float4 v3 = *(const float4*)&Mscr[mswz(s, ro + 12)];
        M2[r][0] = (v2f){v0.x, v0.y}; M2[r][1] = (v2f){v0.z, v0.w};
        M2[r][2] = (v2f){v1.x, v1.y}; M2[r][3] = (v2f){v1.z, v1.w};
        M2[r][4] = (v2f){v2.x, v2.y}; M2[r][5] = (v2f){v2.z, v2.w};
        M2[r][6] = (v2f){v3.x, v3.y}; M2[r][7] = (v2f){v3.z, v3.w};
        r4[r] = racc[r];
        d4[r] = 1.0f;
    }

#pragma unroll
    for (int k = 0; k < 16; ++k) {
        const int src = sl + ((k >> 2) << 4);
        float piv = __shfl(M2[k & 3][k >> 1][k & 1], src, 64);
        float rk  = __shfl(r4[k & 3], src, 64);
        float invp = __builtin_amdgcn_rcpf(piv);
        invp = invp * (2.0f - piv * invp);
        float f[4];
#pragma unroll
        for (int r = 0; r < 4; ++r) {
            float fr = M2[r][k >> 1][k & 1] * invp;
            const bool isk = ((rb << 2) + r) == k;
            f[r]  = isk ? 0.0f : fr;
            d4[r] = isk ? piv : d4[r];
            r4[r] = fmaf(-f[r], rk, r4[r]);
        }
        // pair updates: start at pair containing k (k even: p0 == piv, col-k update is
        // dead-but-harmless; k odd: that pair is entirely eliminated cols -> skip).
        const int i2s = (k >> 1) + (k & 1);
#pragma unroll
        for (int i2 = i2s; i2 < 8; ++i2) {
            float p0 = (2 * i2 == k) ? piv : __shfl(M2[k & 3][i2][0], src, 64);
            float p1 = __shfl(M2[k & 3][i2][1], src, 64);
            v2f pv = {p0, p1};
#pragma unroll
            for (int r = 0; r < 4; ++r) {
                v2f fv = {-f[r], -f[r]};
                M2[r][i2] = __builtin_elementwise_fma(fv, pv, M2[r][i2]);
            }
        }
    }

    float4 xo;
    {
        float i0 = __builtin_amdgcn_rcpf(d4[0]); i0 = i0 * (2.0f - d4[0] * i0);
        float i1 = __builtin_amdgcn_rcpf(d4[1]); i1 = i1 * (2.0f - d4[1] * i1);
        float i2 = __builtin_amdgcn_rcpf(d4[2]); i2 = i2 * (2.0f - d4[2] * i2);
        float i3 = __builtin_amdgcn_rcpf(d4[3]); i3 = i3 * (2.0f - d4[3] * i3);
        xo.x = r4[0] * i0; xo.y = r4[1] * i1; xo.z = r4[2] * i2; xo.w = r4[3] * i3;
    }
    *(float4*)&out[(s0 + s) * DIMQ + (rb << 2)] = xo;
}

extern "C" void kernel_launch(void* const* d_in, const int* in_sizes, int n_in,
                              void* d_out, int out_size, void* d_ws, size_t ws_size,
                              hipStream_t stream) {
    const float* y  = (const float*)d_in[0];
    const float* W1 = (const float*)d_in[1];
    const float* b1 = (const float*)d_in[2];
    const float* w2 = (const float*)d_in[3];
    float* out = (float*)d_out;
    const int batch = in_sizes[0] / 32;          // 32768
    const int blocks = (batch + SPB - 1) / SPB;  // 1024
    lag_accel_kernel<<<blocks, NTHREADS, 0, stream>>>(y, W1, b1, w2, out);
}